// Round 9
// baseline (1041.261 us; speedup 1.0000x reference)
//
#include <hip/hip_runtime.h>
#include <stdint.h>

#define TOKENS 8192
#define HIDDEN 4096
constexpr float EPS = 1e-6f;
constexpr float FP8_MAX = 448.0f;

using f32x4  = __attribute__((ext_vector_type(4))) float;
using f32x16 = __attribute__((ext_vector_type(16))) float;
using i32x4  = __attribute__((ext_vector_type(4))) int;
using i32x8  = __attribute__((ext_vector_type(8))) int;

typedef __attribute__((address_space(3))) uint32_t lds_u32_t;
typedef const __attribute__((address_space(1))) uint32_t glb_u32_t;

// ---------------- fp8 pack helper (OCP e4m3fn, RNE + saturate) ----------------
__device__ inline uint32_t pack_fp8x4(float a, float b, float c, float d) {
    int w = 0;
    w = __builtin_amdgcn_cvt_pk_fp8_f32(a, b, w, false); // bytes 0,1
    w = __builtin_amdgcn_cvt_pk_fp8_f32(c, d, w, true);  // bytes 2,3
    return (uint32_t)w;
}

// ---------------- block reductions (4 waves of 64) ----------------
__device__ inline float block_sum(float v, float* sh, int tid) {
#pragma unroll
    for (int o = 32; o > 0; o >>= 1) v += __shfl_xor(v, o, 64);
    if ((tid & 63) == 0) sh[tid >> 6] = v;
    __syncthreads();
    return sh[0] + sh[1] + sh[2] + sh[3];
}
__device__ inline float block_max(float v, float* sh, int tid) {
#pragma unroll
    for (int o = 32; o > 0; o >>= 1) v = fmaxf(v, __shfl_xor(v, o, 64));
    if ((tid & 63) == 0) sh[tid >> 6] = v;
    __syncthreads();
    return fmaxf(fmaxf(sh[0], sh[1]), fmaxf(sh[2], sh[3]));
}

// ---------------- weight quantization: Wq = fp8(W / s), linear layout ----------------
__launch_bounds__(256)
__global__ void quant_weights(const float* __restrict__ Ws,
                              const float* __restrict__ w_scales,
                              uint8_t* __restrict__ Wq) {
    size_t idx = ((size_t)blockIdx.x * 256 + threadIdx.x) * 8;
    int tensor = (int)(idx / ((size_t)HIDDEN * HIDDEN));
    float inv = 1.0f / w_scales[tensor];
    const float4* src = (const float4*)(Ws + idx);
    float4 v0 = src[0], v1 = src[1];
    uint2 out;
    out.x = pack_fp8x4(v0.x * inv, v0.y * inv, v0.z * inv, v0.w * inv);
    out.y = pack_fp8x4(v1.x * inv, v1.y * inv, v1.z * inv, v1.w * inv);
    *(uint2*)(Wq + idx) = out;
}

// ---------------- relu + rmsnorm + dynamic quant (layer 0 input) ----------------
__launch_bounds__(256)
__global__ void relu_rms_quant(const float* __restrict__ x,
                               const float* __restrict__ nw,   // norm_w row 0
                               float* __restrict__ resid,
                               uint8_t* __restrict__ yq,
                               float* __restrict__ ascale) {
    __shared__ float sh1[4], sh2[4];
    const int row = blockIdx.x, tid = threadIdx.x;
    const float* xr = x + (size_t)row * HIDDEN;
    float* rr = resid + (size_t)row * HIDDEN;

    float4 v[4];
    float ss = 0.f;
#pragma unroll
    for (int c = 0; c < 4; ++c) {
        float4 t = *(const float4*)(xr + c * 1024 + tid * 4);
        t.x = fmaxf(t.x, 0.f); t.y = fmaxf(t.y, 0.f);
        t.z = fmaxf(t.z, 0.f); t.w = fmaxf(t.w, 0.f);
        v[c] = t;
        ss += t.x * t.x + t.y * t.y + t.z * t.z + t.w * t.w;
        *(float4*)(rr + c * 1024 + tid * 4) = t;
    }
    ss = block_sum(ss, sh1, tid);
    float rstd = 1.0f / sqrtf(ss * (1.0f / HIDDEN) + EPS);

    float4 y[4];
    float amax = 0.f;
#pragma unroll
    for (int c = 0; c < 4; ++c) {
        float4 w = *(const float4*)(nw + c * 1024 + tid * 4);
        y[c].x = v[c].x * rstd * w.x; amax = fmaxf(amax, fabsf(y[c].x));
        y[c].y = v[c].y * rstd * w.y; amax = fmaxf(amax, fabsf(y[c].y));
        y[c].z = v[c].z * rstd * w.z; amax = fmaxf(amax, fabsf(y[c].z));
        y[c].w = v[c].w * rstd * w.w; amax = fmaxf(amax, fabsf(y[c].w));
    }
    amax = block_max(amax, sh2, tid);
    float s = fmaxf(amax / FP8_MAX, 1e-12f);
    if (tid == 0) ascale[row] = s;
    float inv = 1.0f / s;
#pragma unroll
    for (int c = 0; c < 4; ++c) {
        uint32_t p = pack_fp8x4(y[c].x * inv, y[c].y * inv, y[c].z * inv, y[c].w * inv);
        *(uint32_t*)(yq + (size_t)row * HIDDEN + c * 1024 + tid * 4) = p;
    }
}

// ---------------- rmsnorm + dynamic quant (between layers) ----------------
__launch_bounds__(256)
__global__ void rms_quant(const float* __restrict__ resid,
                          const float* __restrict__ nw,
                          uint8_t* __restrict__ yq,
                          float* __restrict__ ascale) {
    __shared__ float sh1[4], sh2[4];
    const int row = blockIdx.x, tid = threadIdx.x;
    const float* rr = resid + (size_t)row * HIDDEN;

    float4 v[4];
    float ss = 0.f;
#pragma unroll
    for (int c = 0; c < 4; ++c) {
        float4 t = *(const float4*)(rr + c * 1024 + tid * 4);
        v[c] = t;
        ss += t.x * t.x + t.y * t.y + t.z * t.z + t.w * t.w;
    }
    ss = block_sum(ss, sh1, tid);
    float rstd = 1.0f / sqrtf(ss * (1.0f / HIDDEN) + EPS);

    float4 y[4];
    float amax = 0.f;
#pragma unroll
    for (int c = 0; c < 4; ++c) {
        float4 w = *(const float4*)(nw + c * 1024 + tid * 4);
        y[c].x = v[c].x * rstd * w.x; amax = fmaxf(amax, fabsf(y[c].x));
        y[c].y = v[c].y * rstd * w.y; amax = fmaxf(amax, fabsf(y[c].y));
        y[c].z = v[c].z * rstd * w.z; amax = fmaxf(amax, fabsf(y[c].z));
        y[c].w = v[c].w * rstd * w.w; amax = fmaxf(amax, fabsf(y[c].w));
    }
    amax = block_max(amax, sh2, tid);
    float s = fmaxf(amax / FP8_MAX, 1e-12f);
    if (tid == 0) ascale[row] = s;
    float inv = 1.0f / s;
#pragma unroll
    for (int c = 0; c < 4; ++c) {
        uint32_t p = pack_fp8x4(y[c].x * inv, y[c].y * inv, y[c].z * inv, y[c].w * inv);
        *(uint32_t*)(yq + (size_t)row * HIDDEN + c * 1024 + tid * 4) = p;
    }
}

// ---------------- final rmsnorm -> f32 output ----------------
__launch_bounds__(256)
__global__ void rms_final(const float* __restrict__ resid,
                          const float* __restrict__ nw,
                          float* __restrict__ out) {
    __shared__ float sh1[4];
    const int row = blockIdx.x, tid = threadIdx.x;
    const float* rr = resid + (size_t)row * HIDDEN;

    float4 v[4];
    float ss = 0.f;
#pragma unroll
    for (int c = 0; c < 4; ++c) {
        float4 t = *(const float4*)(rr + c * 1024 + tid * 4);
        v[c] = t;
        ss += t.x * t.x + t.y * t.y + t.z * t.z + t.w * t.w;
    }
    ss = block_sum(ss, sh1, tid);
    float rstd = 1.0f / sqrtf(ss * (1.0f / HIDDEN) + EPS);

#pragma unroll
    for (int c = 0; c < 4; ++c) {
        float4 w = *(const float4*)(nw + c * 1024 + tid * 4);
        float4 o;
        o.x = v[c].x * rstd * w.x;
        o.y = v[c].y * rstd * w.y;
        o.z = v[c].z * rstd * w.z;
        o.w = v[c].w * rstd * w.w;
        *(float4*)(out + (size_t)row * HIDDEN + c * 1024 + tid * 4) = o;
    }
}

// ---------------- fp8 GEMM, 256x256: A direct-to-reg, B-only LDS ----------------
// resid += a_scale[t]*w_scale * (Aq @ Bq^T).  8 waves (2m x 4n), 128x64/wave,
// 32x32x64 MX-scaled MFMA, unit e8m0 scales (= raw fp8 dot, f32 accum).
// A-fragments are wave-private -> load straight from global (L2-resident tile)
// into named VGPR double-buffer, issued 1 tile ahead.  B staged in LDS (NBUF=4,
// 2 tiles ahead, gload_lds).  ONE barrier per 2 K-tiles: stage B(t+2)/B(t+3)
// write bufs (t+2)&3/(t+3)&3 while reads in this region touch (t)&3/(t+1)&3 —
// disjoint; reads of B(t-2)/B(t-1) are separated from the overwrite by bar(t).
// Own-wave vmcnt(10) before the barrier guarantees each wave's B chunks landed.
#define BM 256
#define BN 256
#define BK 64
#define NBUF 4

__launch_bounds__(512, 2)
__global__ void gemm_fp8(const uint8_t* __restrict__ Aq,
                         const uint8_t* __restrict__ Bq,
                         const float* __restrict__ ascale,
                         const float* __restrict__ wscale_p,
                         float* __restrict__ resid) {
    __shared__ __align__(16) uint8_t sB[NBUF][BN * BK];   // 4 x 16 KB
    __shared__ float s_as[BM];

    const int tid = threadIdx.x;
    // XCD-chunked bijective swizzle (grid = 512 = 8 * 64)
    int bid = blockIdx.x;
    bid = (bid & 7) * 64 + (bid >> 3);
    const int nbn = HIDDEN / BN;   // 16
    const int bm = bid / nbn, bn = bid % nbn;
    const int brow = bm * BM, bcol = bn * BN;

    const int wave = tid >> 6, lane = tid & 63;
    const int wm = wave >> 2, wn = wave & 3;   // 2 x 4 wave grid
    const int lr = lane & 31;      // row within 32x32 tile
    const int lh = lane >> 5;      // k-half (which 32B k-block)

    if (tid < BM) s_as[tid] = ascale[brow + tid];

    f32x16 acc[4][2] = {};

    const uint8_t* aSrc = Aq + (size_t)brow * HIDDEN;
    const uint8_t* bSrc = Bq + (size_t)bcol * HIDDEN;

    // A row pointers (wave-private fragment rows), +lh*32 k-offset baked in.
    const uint8_t* aRow[4];
#pragma unroll
    for (int mi = 0; mi < 4; ++mi)
        aRow[mi] = aSrc + (size_t)(wm * 128 + mi * 32 + lr) * HIDDEN + lh * 32;

    // B stager: issue c covers LDS bytes c*8192 + tid*16 -> row = c*128+(tid>>2),
    // granule = tid&3.  LDS[r][g] holds global granule g ^ ((r>>1)&3).
    const int r_st = tid >> 2;            // 0..127
    const int g_st = tid & 3;
    const int gsrc = g_st ^ ((r_st >> 1) & 3);
    const size_t off0 = (size_t)r_st * HIDDEN + gsrc * 16;
    const size_t off1 = (size_t)(r_st + 128) * HIDDEN + gsrc * 16;
    const int ldsw = wave * 1024;         // + lane*16 implicit (uniform base per wave)

    // B reader: two b128s at swizzled granules (2*lh+h) ^ ((row>>1)&3).
    int offB[2][2];
#pragma unroll
    for (int ni = 0; ni < 2; ++ni) {
        int rb = wn * 64 + ni * 32 + lr;
        int sw = (rb >> 1) & 3;
        offB[ni][0] = rb * 64 + ((2 * lh + 0) ^ sw) * 16;
        offB[ni][1] = rb * 64 + ((2 * lh + 1) ^ sw) * 16;
    }

    const int UNIT = 0x7F7F7F7F;  // e8m0 scale = 2^0 in all bytes

    auto stageB = [&](int buf, int kt) {
        const int k0 = kt * BK;
        __builtin_amdgcn_global_load_lds((glb_u32_t*)(bSrc + off0 + k0),
                                         (lds_u32_t*)&sB[buf][ldsw], 16, 0, 0);
        __builtin_amdgcn_global_load_lds((glb_u32_t*)(bSrc + off1 + k0),
                                         (lds_u32_t*)&sB[buf][8192 + ldsw], 16, 0, 0);
    };
    auto loadA = [&](i32x8 (&dst)[4], int kt) {
        const int k0 = kt * BK;
#pragma unroll
        for (int mi = 0; mi < 4; ++mi) {
            i32x4 lo = *(const i32x4*)(aRow[mi] + k0);
            i32x4 hi = *(const i32x4*)(aRow[mi] + k0 + 16);
            dst[mi] = __builtin_shufflevector(lo, hi, 0, 1, 2, 3, 4, 5, 6, 7);
        }
    };
    auto compute = [&](int buf, i32x8 (&A)[4]) {
        i32x4 b0l = *(const i32x4*)&sB[buf][offB[0][0]];
        i32x4 b0h = *(const i32x4*)&sB[buf][offB[0][1]];
        i32x4 b1l = *(const i32x4*)&sB[buf][offB[1][0]];
        i32x4 b1h = *(const i32x4*)&sB[buf][offB[1][1]];
        i32x8 b0 = __builtin_shufflevector(b0l, b0h, 0, 1, 2, 3, 4, 5, 6, 7);
        i32x8 b1 = __builtin_shufflevector(b1l, b1h, 0, 1, 2, 3, 4, 5, 6, 7);
        __builtin_amdgcn_s_setprio(1);
#pragma unroll
        for (int mi = 0; mi < 4; ++mi) {
            acc[mi][0] = __builtin_amdgcn_mfma_scale_f32_32x32x64_f8f6f4(
                A[mi], b0, acc[mi][0], 0, 0, 0, UNIT, 0, UNIT);
            acc[mi][1] = __builtin_amdgcn_mfma_scale_f32_32x32x64_f8f6f4(
                A[mi], b1, acc[mi][1], 0, 0, 0, UNIT, 0, UNIT);
        }
        __builtin_amdgcn_s_setprio(0);
    };

    const int NT = HIDDEN / BK;   // 64
    i32x8 A0[4], A1[4];

    // prologue: B tiles 0,1 staged; A tile 0 in regs (in flight).
    stageB(0, 0); stageB(1, 1);
    loadA(A0, 0);

#pragma unroll 1
    for (int t = 0; t < NT; t += 2) {
        // ---- even tile t: compute with A0 ----
        if (t + 2 < NT) stageB((t + 2) & 3, t + 2);
        loadA(A1, t + 1);
        if (t + 2 < NT) asm volatile("s_waitcnt vmcnt(10)" ::: "memory");
        else            asm volatile("s_waitcnt vmcnt(8)"  ::: "memory");
        __builtin_amdgcn_s_barrier();      // once per 2 tiles
        compute(t & 3, A0);

        // ---- odd tile t+1: compute with A1 ----
        if (t + 3 < NT) stageB((t + 3) & 3, t + 3);
        if (t + 2 < NT) loadA(A0, t + 2);
        if (t + 3 < NT)      asm volatile("s_waitcnt vmcnt(10)" ::: "memory");
        else if (t + 2 < NT) asm volatile("s_waitcnt vmcnt(8)"  ::: "memory");
        else                 asm volatile("s_waitcnt vmcnt(0)"  ::: "memory");
        compute((t + 1) & 3, A1);
    }

    const float wsc = *wscale_p;
#pragma unroll
    for (int mi = 0; mi < 4; ++mi) {
        float alpha[16];
#pragma unroll
        for (int i = 0; i < 16; ++i) {
            const int rl = (i & 3) + 8 * (i >> 2) + 4 * lh;
            alpha[i] = s_as[wm * 128 + mi * 32 + rl] * wsc;
        }
#pragma unroll
        for (int ni = 0; ni < 2; ++ni) {
            const int col = bcol + wn * 64 + ni * 32 + lr;
#pragma unroll
            for (int i = 0; i < 16; ++i) {
                const int rl = (i & 3) + 8 * (i >> 2) + 4 * lh;
                const int row_local = wm * 128 + mi * 32 + rl;
                const size_t o = (size_t)(brow + row_local) * HIDDEN + col;
                resid[o] += acc[mi][ni][i] * alpha[i];
            }
        }
    }
}

// ---------------- launch ----------------
extern "C" void kernel_launch(void* const* d_in, const int* in_sizes, int n_in,
                              void* d_out, int out_size, void* d_ws, size_t ws_size,
                              hipStream_t stream) {
    const float* x   = (const float*)d_in[0];
    const float* nw  = (const float*)d_in[1];
    const float* Ws  = (const float*)d_in[2];
    const float* wsc = (const float*)d_in[3];
    float* out = (float*)d_out;

    uint8_t* ws = (uint8_t*)d_ws;
    float*   resid  = (float*)ws;                                  // 128 MiB
    uint8_t* yq     = ws + (size_t)TOKENS * HIDDEN * 4;            // 32 MiB
    uint8_t* Wq     = yq + (size_t)TOKENS * HIDDEN;                // 48 MiB
    float*   ascale = (float*)(Wq + (size_t)3 * HIDDEN * HIDDEN);  // 32 KiB

    // quantize weights (3 * H * H elements, 8 per thread)
    quant_weights<<<(3 * (size_t)HIDDEN * HIDDEN) / 2048, 256, 0, stream>>>(Ws, wsc, Wq);

    // relu + rmsnorm(norm_w[0]) + quant
    relu_rms_quant<<<TOKENS, 256, 0, stream>>>(x, nw, resid, yq, ascale);

    for (int i = 0; i < 3; ++i) {
        gemm_fp8<<<(TOKENS / BM) * (HIDDEN / BN), 512, 0, stream>>>(
            yq, Wq + (size_t)i * HIDDEN * HIDDEN, ascale, wsc + i, resid);
        if (i < 2)
            rms_quant<<<TOKENS, 256, 0, stream>>>(resid, nw + (size_t)(i + 1) * HIDDEN, yq, ascale);
        else
            rms_final<<<TOKENS, 256, 0, stream>>>(resid, nw + (size_t)3 * HIDDEN, out);
    }
}

// Round 11
// 677.446 us; speedup vs baseline: 1.5370x; 1.5370x over previous
//
#include <hip/hip_runtime.h>
#include <stdint.h>

#define TOKENS 8192
#define HIDDEN 4096
constexpr float EPS = 1e-6f;
constexpr float FP8_MAX = 448.0f;

using f32x4  = __attribute__((ext_vector_type(4))) float;
using i32x4  = __attribute__((ext_vector_type(4))) int;
using i32x8  = __attribute__((ext_vector_type(8))) int;

typedef __attribute__((address_space(3))) uint32_t lds_u32_t;
typedef const __attribute__((address_space(1))) uint32_t glb_u32_t;

// ---------------- fp8 pack helper (OCP e4m3fn, RNE + saturate) ----------------
__device__ inline uint32_t pack_fp8x4(float a, float b, float c, float d) {
    int w = 0;
    w = __builtin_amdgcn_cvt_pk_fp8_f32(a, b, w, false); // bytes 0,1
    w = __builtin_amdgcn_cvt_pk_fp8_f32(c, d, w, true);  // bytes 2,3
    return (uint32_t)w;
}

// ---------------- block reductions (4 waves of 64) ----------------
__device__ inline float block_sum(float v, float* sh, int tid) {
#pragma unroll
    for (int o = 32; o > 0; o >>= 1) v += __shfl_xor(v, o, 64);
    if ((tid & 63) == 0) sh[tid >> 6] = v;
    __syncthreads();
    return sh[0] + sh[1] + sh[2] + sh[3];
}
__device__ inline float block_max(float v, float* sh, int tid) {
#pragma unroll
    for (int o = 32; o > 0; o >>= 1) v = fmaxf(v, __shfl_xor(v, o, 64));
    if ((tid & 63) == 0) sh[tid >> 6] = v;
    __syncthreads();
    return fmaxf(fmaxf(sh[0], sh[1]), fmaxf(sh[2], sh[3]));
}

// ---------------- weight quantization: Wq = fp8(W / s), linear layout ----------------
__launch_bounds__(256)
__global__ void quant_weights(const float* __restrict__ Ws,
                              const float* __restrict__ w_scales,
                              uint8_t* __restrict__ Wq) {
    size_t idx = ((size_t)blockIdx.x * 256 + threadIdx.x) * 8;
    int tensor = (int)(idx / ((size_t)HIDDEN * HIDDEN));
    float inv = 1.0f / w_scales[tensor];
    const float4* src = (const float4*)(Ws + idx);
    float4 v0 = src[0], v1 = src[1];
    uint2 out;
    out.x = pack_fp8x4(v0.x * inv, v0.y * inv, v0.z * inv, v0.w * inv);
    out.y = pack_fp8x4(v1.x * inv, v1.y * inv, v1.z * inv, v1.w * inv);
    *(uint2*)(Wq + idx) = out;
}

// ---------------- relu + rmsnorm + dynamic quant (layer 0 input) ----------------
__launch_bounds__(256)
__global__ void relu_rms_quant(const float* __restrict__ x,
                               const float* __restrict__ nw,   // norm_w row 0
                               float* __restrict__ resid,
                               uint8_t* __restrict__ yq,
                               float* __restrict__ ascale) {
    __shared__ float sh1[4], sh2[4];
    const int row = blockIdx.x, tid = threadIdx.x;
    const float* xr = x + (size_t)row * HIDDEN;
    float* rr = resid + (size_t)row * HIDDEN;

    float4 v[4];
    float ss = 0.f;
#pragma unroll
    for (int c = 0; c < 4; ++c) {
        float4 t = *(const float4*)(xr + c * 1024 + tid * 4);
        t.x = fmaxf(t.x, 0.f); t.y = fmaxf(t.y, 0.f);
        t.z = fmaxf(t.z, 0.f); t.w = fmaxf(t.w, 0.f);
        v[c] = t;
        ss += t.x * t.x + t.y * t.y + t.z * t.z + t.w * t.w;
        *(float4*)(rr + c * 1024 + tid * 4) = t;
    }
    ss = block_sum(ss, sh1, tid);
    float rstd = 1.0f / sqrtf(ss * (1.0f / HIDDEN) + EPS);

    float4 y[4];
    float amax = 0.f;
#pragma unroll
    for (int c = 0; c < 4; ++c) {
        float4 w = *(const float4*)(nw + c * 1024 + tid * 4);
        y[c].x = v[c].x * rstd * w.x; amax = fmaxf(amax, fabsf(y[c].x));
        y[c].y = v[c].y * rstd * w.y; amax = fmaxf(amax, fabsf(y[c].y));
        y[c].z = v[c].z * rstd * w.z; amax = fmaxf(amax, fabsf(y[c].z));
        y[c].w = v[c].w * rstd * w.w; amax = fmaxf(amax, fabsf(y[c].w));
    }
    amax = block_max(amax, sh2, tid);
    float s = fmaxf(amax / FP8_MAX, 1e-12f);
    if (tid == 0) ascale[row] = s;
    float inv = 1.0f / s;
#pragma unroll
    for (int c = 0; c < 4; ++c) {
        uint32_t p = pack_fp8x4(y[c].x * inv, y[c].y * inv, y[c].z * inv, y[c].w * inv);
        *(uint32_t*)(yq + (size_t)row * HIDDEN + c * 1024 + tid * 4) = p;
    }
}

// ---------------- rmsnorm + dynamic quant (between layers) ----------------
__launch_bounds__(256)
__global__ void rms_quant(const float* __restrict__ resid,
                          const float* __restrict__ nw,
                          uint8_t* __restrict__ yq,
                          float* __restrict__ ascale) {
    __shared__ float sh1[4], sh2[4];
    const int row = blockIdx.x, tid = threadIdx.x;
    const float* rr = resid + (size_t)row * HIDDEN;

    float4 v[4];
    float ss = 0.f;
#pragma unroll
    for (int c = 0; c < 4; ++c) {
        float4 t = *(const float4*)(rr + c * 1024 + tid * 4);
        v[c] = t;
        ss += t.x * t.x + t.y * t.y + t.z * t.z + t.w * t.w;
    }
    ss = block_sum(ss, sh1, tid);
    float rstd = 1.0f / sqrtf(ss * (1.0f / HIDDEN) + EPS);

    float4 y[4];
    float amax = 0.f;
#pragma unroll
    for (int c = 0; c < 4; ++c) {
        float4 w = *(const float4*)(nw + c * 1024 + tid * 4);
        y[c].x = v[c].x * rstd * w.x; amax = fmaxf(amax, fabsf(y[c].x));
        y[c].y = v[c].y * rstd * w.y; amax = fmaxf(amax, fabsf(y[c].y));
        y[c].z = v[c].z * rstd * w.z; amax = fmaxf(amax, fabsf(y[c].z));
        y[c].w = v[c].w * rstd * w.w; amax = fmaxf(amax, fabsf(y[c].w));
    }
    amax = block_max(amax, sh2, tid);
    float s = fmaxf(amax / FP8_MAX, 1e-12f);
    if (tid == 0) ascale[row] = s;
    float inv = 1.0f / s;
#pragma unroll
    for (int c = 0; c < 4; ++c) {
        uint32_t p = pack_fp8x4(y[c].x * inv, y[c].y * inv, y[c].z * inv, y[c].w * inv);
        *(uint32_t*)(yq + (size_t)row * HIDDEN + c * 1024 + tid * 4) = p;
    }
}

// ---------------- final rmsnorm -> f32 output ----------------
__launch_bounds__(256)
__global__ void rms_final(const float* __restrict__ resid,
                          const float* __restrict__ nw,
                          float* __restrict__ out) {
    __shared__ float sh1[4];
    const int row = blockIdx.x, tid = threadIdx.x;
    const float* rr = resid + (size_t)row * HIDDEN;

    float4 v[4];
    float ss = 0.f;
#pragma unroll
    for (int c = 0; c < 4; ++c) {
        float4 t = *(const float4*)(rr + c * 1024 + tid * 4);
        v[c] = t;
        ss += t.x * t.x + t.y * t.y + t.z * t.z + t.w * t.w;
    }
    ss = block_sum(ss, sh1, tid);
    float rstd = 1.0f / sqrtf(ss * (1.0f / HIDDEN) + EPS);

#pragma unroll
    for (int c = 0; c < 4; ++c) {
        float4 w = *(const float4*)(nw + c * 1024 + tid * 4);
        float4 o;
        o.x = v[c].x * rstd * w.x;
        o.y = v[c].y * rstd * w.y;
        o.z = v[c].z * rstd * w.z;
        o.w = v[c].w * rstd * w.w;
        *(float4*)(out + (size_t)row * HIDDEN + c * 1024 + tid * 4) = o;
    }
}

// ---------------- fp8 GEMM, m148 structure: 128x128, BK=128, 16x16x128 MX ----------------
// resid += a_scale[t]*w_scale * (Aq @ Bq^T).  4 waves (2m x 2n), 64x64/wave =
// 4x4 frags of 16x16; mfma_scale_f32_16x16x128_f8f6f4, unit e8m0 scales.
// Single 32KB LDS buffer, plain {sync; stage; sync; compute} loop — overlap via
// 2 blocks/CU occupancy (m97/m148-proven).  A-frag: lane holds row (lane&15),
// k-bytes (lane>>4)*32 — two b128 at granules (2kh, 2kh+1) ^ (row&7).
// Swizzle bank math: rows 0..15 at fixed kh hit all 8 16B-slots (XOR perm),
// 2 lanes/slot -> 2-way aliasing = free.  Stager: 4 issues/matrix, thread ->
// row c*32+(tid>>3), granule (tid&7)^(row&7); LDS stays linear (dest tid*16).
#define BM 128
#define BN 128
#define BK 128

__launch_bounds__(256, 2)
__global__ void gemm_fp8(const uint8_t* __restrict__ Aq,
                         const uint8_t* __restrict__ Bq,
                         const float* __restrict__ ascale,
                         const float* __restrict__ wscale_p,
                         float* __restrict__ resid) {
    __shared__ __align__(16) uint8_t sA[BM * BK];   // 16 KB
    __shared__ __align__(16) uint8_t sB[BN * BK];   // 16 KB
    __shared__ float s_as[BM];

    const int tid = threadIdx.x;
    // XCD-chunked bijective swizzle (grid = 2048 = 8 * 256)
    int bid = blockIdx.x;
    bid = (bid & 7) * 256 + (bid >> 3);
    const int nbn = HIDDEN / BN;   // 32
    const int bm = bid / nbn, bn = bid % nbn;
    const int brow = bm * BM, bcol = bn * BN;

    const int wave = tid >> 6, lane = tid & 63;
    const int wm = wave >> 1, wn = wave & 1;   // 2 x 2 wave grid
    const int lr = lane & 15;      // row within 16x16 tile
    const int kh = lane >> 4;      // k-quarter (which 32B k-block)

    if (tid < BM) s_as[tid] = ascale[brow + tid];

    f32x4 acc[4][4] = {};

    const uint8_t* aSrc = Aq + (size_t)brow * HIDDEN;
    const uint8_t* bSrc = Bq + (size_t)bcol * HIDDEN;

    // Stager: issue c covers LDS bytes c*4096 + tid*16 -> row = c*32 + (tid>>3),
    // granule = tid&7.  LDS[r][g] holds global granule g ^ (r&7).
    const int r_st = tid >> 3;            // 0..31
    const int g_st = tid & 7;
    const int gsrc = g_st ^ (r_st & 7);   // (c*32 + r_st)&7 == r_st&7
    const size_t offst = (size_t)r_st * HIDDEN + gsrc * 16;
    const int ldsw = wave * 1024;         // + lane*16 implicit (uniform base per wave)

    // Reader: lane fragment = 32 contiguous k-bytes of one row, two b128s at
    // granules (2*kh+h) ^ (row&7); byte offset row*128 + g*16.
    int offA[4][2], offB[4][2];
#pragma unroll
    for (int i = 0; i < 4; ++i) {
        int ra = wm * 64 + i * 16 + lr;
        offA[i][0] = ra * 128 + ((2 * kh + 0) ^ (ra & 7)) * 16;
        offA[i][1] = ra * 128 + ((2 * kh + 1) ^ (ra & 7)) * 16;
        int rb = wn * 64 + i * 16 + lr;
        offB[i][0] = rb * 128 + ((2 * kh + 0) ^ (rb & 7)) * 16;
        offB[i][1] = rb * 128 + ((2 * kh + 1) ^ (rb & 7)) * 16;
    }

    const int UNIT = 0x7F7F7F7F;  // e8m0 scale = 2^0 in all bytes

    auto rdfrag = [&](const uint8_t* base, const int* off) -> i32x8 {
        i32x4 lo = *(const i32x4*)&base[off[0]];
        i32x4 hi = *(const i32x4*)&base[off[1]];
        return __builtin_shufflevector(lo, hi, 0, 1, 2, 3, 4, 5, 6, 7);
    };

#pragma unroll 1
    for (int k0 = 0; k0 < HIDDEN; k0 += BK) {
        __syncthreads();                       // buffer free (WAR)
#pragma unroll
        for (int c = 0; c < 4; ++c) {
            __builtin_amdgcn_global_load_lds(
                (glb_u32_t*)(aSrc + offst + (size_t)c * 32 * HIDDEN + k0),
                (lds_u32_t*)&sA[c * 4096 + ldsw], 16, 0, 0);
            __builtin_amdgcn_global_load_lds(
                (glb_u32_t*)(bSrc + offst + (size_t)c * 32 * HIDDEN + k0),
                (lds_u32_t*)&sB[c * 4096 + ldsw], 16, 0, 0);
        }
        __syncthreads();                       // tile staged (vmcnt drained)

        // B frags first, then interleave A reads with MFMA rows.
        i32x8 b0 = rdfrag(sB, offB[0]);
        i32x8 b1 = rdfrag(sB, offB[1]);
        i32x8 b2 = rdfrag(sB, offB[2]);
        i32x8 b3 = rdfrag(sB, offB[3]);
        i32x8 a = rdfrag(sA, offA[0]);
#pragma unroll
        for (int mi = 0; mi < 4; ++mi) {
            i32x8 a_cur = a;
            if (mi < 3) a = rdfrag(sA, offA[mi + 1]);
            acc[mi][0] = __builtin_amdgcn_mfma_scale_f32_16x16x128_f8f6f4(
                a_cur, b0, acc[mi][0], 0, 0, 0, UNIT, 0, UNIT);
            acc[mi][1] = __builtin_amdgcn_mfma_scale_f32_16x16x128_f8f6f4(
                a_cur, b1, acc[mi][1], 0, 0, 0, UNIT, 0, UNIT);
            acc[mi][2] = __builtin_amdgcn_mfma_scale_f32_16x16x128_f8f6f4(
                a_cur, b2, acc[mi][2], 0, 0, 0, UNIT, 0, UNIT);
            acc[mi][3] = __builtin_amdgcn_mfma_scale_f32_16x16x128_f8f6f4(
                a_cur, b3, acc[mi][3], 0, 0, 0, UNIT, 0, UNIT);
        }
    }

    const float wsc = *wscale_p;
#pragma unroll
    for (int mi = 0; mi < 4; ++mi) {
        float alpha[4];
#pragma unroll
        for (int r = 0; r < 4; ++r)
            alpha[r] = s_as[wm * 64 + mi * 16 + kh * 4 + r] * wsc;
#pragma unroll
        for (int ni = 0; ni < 4; ++ni) {
            const int col = bcol + wn * 64 + ni * 16 + lr;
#pragma unroll
            for (int r = 0; r < 4; ++r) {
                const int row = brow + wm * 64 + mi * 16 + kh * 4 + r;
                const size_t o = (size_t)row * HIDDEN + col;
                resid[o] += acc[mi][ni][r] * alpha[r];
            }
        }
    }
}

// ---------------- launch ----------------
extern "C" void kernel_launch(void* const* d_in, const int* in_sizes, int n_in,
                              void* d_out, int out_size, void* d_ws, size_t ws_size,
                              hipStream_t stream) {
    const float* x   = (const float*)d_in[0];
    const float* nw  = (const float*)d_in[1];
    const float* Ws  = (const float*)d_in[2];
    const float* wsc = (const float*)d_in[3];
    float* out = (float*)d_out;

    uint8_t* ws = (uint8_t*)d_ws;
    float*   resid  = (float*)ws;                                  // 128 MiB
    uint8_t* yq     = ws + (size_t)TOKENS * HIDDEN * 4;            // 32 MiB
    uint8_t* Wq     = yq + (size_t)TOKENS * HIDDEN;                // 48 MiB
    float*   ascale = (float*)(Wq + (size_t)3 * HIDDEN * HIDDEN);  // 32 KiB

    // quantize weights (3 * H * H elements, 8 per thread)
    quant_weights<<<(3 * (size_t)HIDDEN * HIDDEN) / 2048, 256, 0, stream>>>(Ws, wsc, Wq);

    // relu + rmsnorm(norm_w[0]) + quant
    relu_rms_quant<<<TOKENS, 256, 0, stream>>>(x, nw, resid, yq, ascale);

    for (int i = 0; i < 3; ++i) {
        gemm_fp8<<<(TOKENS / BM) * (HIDDEN / BN), 256, 0, stream>>>(
            yq, Wq + (size_t)i * HIDDEN * HIDDEN, ascale, wsc + i, resid);
        if (i < 2)
            rms_quant<<<TOKENS, 256, 0, stream>>>(resid, nw + (size_t)(i + 1) * HIDDEN, yq, ascale);
        else
            rms_final<<<TOKENS, 256, 0, stream>>>(resid, nw + (size_t)3 * HIDDEN, out);
    }
}